// Round 4
// baseline (284.725 us; speedup 1.0000x reference)
//
#include <hip/hip_runtime.h>
#include <math.h>

#define B_     1024
#define T_     80
#define D_     512
#define C_     78      // VOCAB+1
#define PRED_  30
#define BLANK_ 77
#define NKK    16      // 512 / 32
#define FRAG   512     // ushorts per fragment block (64 lanes * 8 halves)
#define PLANE_STRIDE (5 * NKK * FRAG)   // 40960 ushorts per plane
#define ROWS_PB 80     // rows per block (1 batch element)
#define A_BYTES (ROWS_PB * 128)            // 10240 B per A slice (80 rows x 32 f32)
#define SLICE_BYTES (A_BYTES + 10 * 1024)  // + 10 B-fragments (5ct x 2 planes) = 20480

typedef __attribute__((ext_vector_type(8))) _Float16 f16x8;
typedef __attribute__((ext_vector_type(4))) float    f32x4;

#define WAITVM(N) asm volatile("s_waitcnt vmcnt(" #N ")" ::: "memory")

__device__ __forceinline__ void load_lds16(const void* g, void* l) {
    __builtin_amdgcn_global_load_lds(
        (const __attribute__((address_space(1))) unsigned int*)g,
        (__attribute__((address_space(3))) unsigned int*)l, 16, 0, 0);
}

// Split W [512,78] fp32 into two f16 planes (w1 = rnd(w), w2 = rnd(w - w1)),
// fragment-linear: [plane][ct][kk][lane][j] -> stage load = base + lane*16B.
__global__ __launch_bounds__(256) void prep_w(const float* __restrict__ W,
                                              ushort* __restrict__ Wf) {
    int i = blockIdx.x * 256 + threadIdx.x;
    if (i >= 2 * PLANE_STRIDE) return;
    int j    = i & 7;
    int lane = (i >> 3) & 63;
    int kk   = (i >> 9) & 15;
    int rest = i >> 13;          // plane*5 + ct
    int ct   = rest % 5;
    int plane = rest / 5;
    int q = lane >> 4, n = lane & 15;
    int k = kk * 32 + q * 8 + j;
    int c = ct * 16 + n;
    float v = (c < C_) ? W[k * C_ + c] : 0.f;
    _Float16 h1 = (_Float16)v;
    union { _Float16 h; ushort u; } cv;
    cv.h = (plane == 0) ? h1 : (_Float16)(v - (float)h1);
    Wf[i] = cv.u;
}

// Block = 320 threads (5 waves) = ONE batch element (80 rows). Wave w owns the
// 16-row tile [w*16, w*16+16), all 78 (pad 80) cols.
// PIPELINE (T3/T4): each K-slice (A rows + that kk's 10 B fragments) staged
// into LDS via global_load_lds, triple-buffered, 2 slices ahead; counted
// `s_waitcnt vmcnt(4)` retires exactly slice k while k+1/k+2 stay in flight
// ACROSS the raw s_barrier. 60 KB LDS -> 2 blocks/CU (TLP fills bubbles).
__global__ __launch_bounds__(320) void gemm_ctc(
    const float* __restrict__ feat,   // [81920, 512] fp32
    const ushort* __restrict__ Wf,    // f16 split planes, fragment-linear
    const float* __restrict__ bias,   // [78] fp32
    float* __restrict__ probs,        // [81920, 78] fp32
    float* __restrict__ lab)          // [1024, 30] fp32
{
    __shared__ __align__(16) unsigned char Sbuf[3][SLICE_BYTES];  // 3 x 20 KB
    __shared__ int best_s[T_];

    const int tid  = threadIdx.x;
    const int w    = tid >> 6;
    const int lane = tid & 63;
    const int q    = lane >> 4;
    const int n    = lane & 15;

    const float* Abase = feat + (size_t)blockIdx.x * ROWS_PB * D_;

    // stage slice kk into buffer buf: A = 80x32 f32 (XOR-swizzled 16B chunks:
    // LDS chunk pos (row,pc) holds global chunk pc ^ (row&7)); B = 10 x 1KB
    // fragments (slot f = plane*5+ct), linear.  4 loads per thread.
    auto stage = [&](int buf, int kk) {
        #pragma unroll
        for (int l = 0; l < 2; ++l) {
            int rb  = w * 2 + l;             // 0..9 (8-row groups)
            int row = rb * 8 + (lane >> 3);
            int pc  = lane & 7;
            int sc  = pc ^ (row & 7);
            const float* g = Abase + (size_t)row * D_ + kk * 32 + sc * 4;
            load_lds16(g, Sbuf[buf] + rb * 1024);   // dst wave-uniform
        }
        #pragma unroll
        for (int f2 = 0; f2 < 2; ++f2) {
            int f     = w * 2 + f2;          // 0..9
            int plane = f / 5, ct = f % 5;
            const ushort* g = Wf + (size_t)plane * PLANE_STRIDE
                                 + (ct * NKK + kk) * FRAG + lane * 8;
            load_lds16(g, Sbuf[buf] + A_BYTES + f * 1024);
        }
    };

    f32x4 acc[5];
    #pragma unroll
    for (int ct = 0; ct < 5; ++ct)
        acc[ct] = (f32x4){0.f, 0.f, 0.f, 0.f};

    auto body = [&](int buf) {
        const float*  Ab = (const float*)(Sbuf[buf]);
        const ushort* Bb = (const ushort*)(Sbuf[buf] + A_BYTES);
        int rowl = w * 16 + n;
        int sw   = n & 7;                    // rowl&7 == n&7 (base mult of 16)
        float4 f0 = *(const float4*)(Ab + rowl * 32 + (((2 * q)     ^ sw) * 4));
        float4 f1 = *(const float4*)(Ab + rowl * 32 + (((2 * q + 1) ^ sw) * 4));
        float v[8] = {f0.x, f0.y, f0.z, f0.w, f1.x, f1.y, f1.z, f1.w};
        f16x8 a1f, a2f;
        #pragma unroll
        for (int j = 0; j < 8; ++j) {
            _Float16 h = (_Float16)v[j];
            a1f[j] = h;
            a2f[j] = (_Float16)(v[j] - (float)h);
        }
        #pragma unroll
        for (int ct = 0; ct < 5; ++ct) {
            f16x8 b1 = *(const f16x8*)(Bb + ct * 512       + lane * 8);
            f16x8 b2 = *(const f16x8*)(Bb + (5 + ct) * 512 + lane * 8);
            acc[ct] = __builtin_amdgcn_mfma_f32_16x16x32_f16(a1f, b1, acc[ct], 0, 0, 0);
            acc[ct] = __builtin_amdgcn_mfma_f32_16x16x32_f16(a2f, b1, acc[ct], 0, 0, 0);
            acc[ct] = __builtin_amdgcn_mfma_f32_16x16x32_f16(a1f, b2, acc[ct], 0, 0, 0);
        }
    };

    // prologue: slices 0,1 in flight (8 loads/thread)
    stage(0, 0);
    stage(1, 1);

    for (int kk = 0; kk < 15; ++kk) {
        WAITVM(4);                           // own slice-k loads retired
        __builtin_amdgcn_s_barrier();        // everyone's slice k is in LDS
        if (kk <= 13) stage((kk + 2) % 3, kk + 2);  // overwrites buf read @ kk-1
        body(kk % 3);
    }
    WAITVM(0);                               // last slice (15)
    __builtin_amdgcn_s_barrier();
    body(0);                                 // 15 % 3 == 0

    // ---- epilogue: bias + argmax + softmax + nontemporal stores ----
    float x[5][4];
    #pragma unroll
    for (int ct = 0; ct < 5; ++ct) {
        int c = ct * 16 + n;
        bool valid = (c < C_);
        float bv = valid ? bias[c] : 0.f;
        #pragma unroll
        for (int r = 0; r < 4; ++r)
            x[ct][r] = valid ? (acc[ct][r] + bv) : -INFINITY;
    }
    float av[4]; int ai[4];
    #pragma unroll
    for (int r = 0; r < 4; ++r) {
        av[r] = x[0][r]; ai[r] = n;
        #pragma unroll
        for (int ct = 1; ct < 5; ++ct) {
            int c = ct * 16 + n;
            if (x[ct][r] > av[r]) { av[r] = x[ct][r]; ai[r] = c; }
        }
    }
    #pragma unroll
    for (int off = 8; off >= 1; off >>= 1) {
        #pragma unroll
        for (int r = 0; r < 4; ++r) {
            float ov = __shfl_xor(av[r], off, 16);
            int   oi = __shfl_xor(ai[r], off, 16);
            if (ov > av[r] || (ov == av[r] && oi < ai[r])) { av[r] = ov; ai[r] = oi; }
        }
    }
    float s[4] = {0.f, 0.f, 0.f, 0.f};
    #pragma unroll
    for (int ct = 0; ct < 5; ++ct)
        #pragma unroll
        for (int r = 0; r < 4; ++r) {
            x[ct][r] = __expf(x[ct][r] - av[r]);   // -INF -> 0
            s[r] += x[ct][r];
        }
    #pragma unroll
    for (int off = 8; off >= 1; off >>= 1)
        #pragma unroll
        for (int r = 0; r < 4; ++r) s[r] += __shfl_xor(s[r], off, 16);

    // wave w covers global rows blk*80 + w*16 + q*4 + r
    const size_t growb = (size_t)blockIdx.x * ROWS_PB + w * 16 + q * 4;
    #pragma unroll
    for (int r = 0; r < 4; ++r) {
        float inv = 1.f / s[r];
        float* op = probs + (growb + r) * C_;
        #pragma unroll
        for (int ct = 0; ct < 5; ++ct) {
            int c = ct * 16 + n;
            if (c < C_) __builtin_nontemporal_store(x[ct][r] * inv, op + c);
        }
    }
    if (n == 0) {
        int rl = w * 16 + q * 4;             // time index within batch element
        #pragma unroll
        for (int r = 0; r < 4; ++r)
            best_s[rl + r] = ai[r];
    }
    __syncthreads();

    // in-block CTC greedy decode (1 batch element)
    if (tid == 0) {
        float* op = lab + (size_t)blockIdx.x * PRED_;
        int prev = -1, pos = 0;
        for (int t2 = 0; t2 < T_; ++t2) {
            int v = best_s[t2];
            if (v != BLANK_ && v != prev) {
                if (pos < PRED_) op[pos] = (float)v;
                ++pos;
            }
            prev = v;
        }
        for (int i2 = (pos < PRED_ ? pos : PRED_); i2 < PRED_; ++i2) op[i2] = -1.f;
    }
}

extern "C" void kernel_launch(void* const* d_in, const int* in_sizes, int n_in,
                              void* d_out, int out_size, void* d_ws, size_t ws_size,
                              hipStream_t stream) {
    const float* feat = (const float*)d_in[0];   // fp32 [1024,80,512]
    const float* W    = (const float*)d_in[1];   // fp32 [512,78]
    const float* bias = (const float*)d_in[2];   // fp32 [78]
    // d_in[3]=y, d_in[4]=times : unused
    float*  probs = (float*)d_out;
    float*  lab   = probs + (size_t)B_ * T_ * C_;
    ushort* Wf    = (ushort*)d_ws;               // 163840 B scratch

    hipLaunchKernelGGL(prep_w, dim3(320), dim3(256), 0, stream, W, Wf);
    hipLaunchKernelGGL(gemm_ctc, dim3(B_), dim3(320), 0, stream,
                       feat, Wf, bias, probs, lab);
}

// Round 5
// 259.386 us; speedup vs baseline: 1.0977x; 1.0977x over previous
//
#include <hip/hip_runtime.h>
#include <math.h>

#define B_     1024
#define T_     80
#define D_     512
#define C_     78      // VOCAB+1
#define PRED_  30
#define BLANK_ 77
#define NKK    16      // 512 / 32
#define FRAG   512     // ushorts per fragment block (64 lanes * 8 halves)
#define PLANE_STRIDE (5 * NKK * FRAG)   // 40960 ushorts per plane
#define ROWS_PB 320    // rows per block (4 batch elements)
#define A_BYTES (ROWS_PB * 128)            // 40960 B per A slice (320 rows x 32 f32)
#define SLICE_BYTES (A_BYTES + 10 * 1024)  // + 10 B-fragments (5ct x 2 planes) = 51200

typedef __attribute__((ext_vector_type(8))) _Float16 f16x8;
typedef __attribute__((ext_vector_type(4))) float    f32x4;

#define WAITVM(N) asm volatile("s_waitcnt vmcnt(" #N ")" ::: "memory")

__device__ __forceinline__ void load_lds16(const void* g, void* l) {
    __builtin_amdgcn_global_load_lds(
        (const __attribute__((address_space(1))) unsigned int*)g,
        (__attribute__((address_space(3))) unsigned int*)l, 16, 0, 0);
}

// Split W [512,78] fp32 into two f16 planes (w1 = rnd(w), w2 = rnd(w - w1)),
// fragment-linear: [plane][ct][kk][lane][j] -> stage load = base + lane*16B.
__global__ __launch_bounds__(256) void prep_w(const float* __restrict__ W,
                                              ushort* __restrict__ Wf) {
    int i = blockIdx.x * 256 + threadIdx.x;
    if (i >= 2 * PLANE_STRIDE) return;
    int j    = i & 7;
    int lane = (i >> 3) & 63;
    int kk   = (i >> 9) & 15;
    int rest = i >> 13;          // plane*5 + ct
    int ct   = rest % 5;
    int plane = rest / 5;
    int q = lane >> 4, n = lane & 15;
    int k = kk * 32 + q * 8 + j;
    int c = ct * 16 + n;
    float v = (c < C_) ? W[k * C_ + c] : 0.f;
    _Float16 h1 = (_Float16)v;
    union { _Float16 h; ushort u; } cv;
    cv.h = (plane == 0) ? h1 : (_Float16)(v - (float)h1);
    Wf[i] = cv.u;
}

// Block = 640 threads (10 waves) = 4 batch elements (320 rows) = ONE block/CU
// (grid 256). Wave w: rows [w*32, w*32+32) as two 16-row MFMA tiles, all 78
// (pad 80) cols. Minimal serial depth per CU: 1 prologue + 16 slices + 1
// epilogue. PIPELINE (T3/T4): each K-slice (A 40KB + B 10KB) staged into LDS
// via global_load_lds (5 loads/thread), triple-buffered, 2 slices ahead;
// counted `s_waitcnt vmcnt(5)` retires exactly slice k while k+1/k+2 stay in
// flight ACROSS the raw s_barrier — never drains to 0 in the main loop.
__global__ __launch_bounds__(640) void gemm_ctc(
    const float* __restrict__ feat,   // [81920, 512] fp32
    const ushort* __restrict__ Wf,    // f16 split planes, fragment-linear
    const float* __restrict__ bias,   // [78] fp32
    float* __restrict__ probs,        // [81920, 78] fp32
    float* __restrict__ lab)          // [1024, 30] fp32
{
    __shared__ __align__(16) unsigned char Sbuf[3][SLICE_BYTES];  // 3 x 50 KB
    __shared__ int best_s[4][T_];

    const int tid  = threadIdx.x;
    const int w    = tid >> 6;      // 0..9
    const int lane = tid & 63;
    const int q    = lane >> 4;
    const int n    = lane & 15;

    const float* Abase = feat + (size_t)blockIdx.x * ROWS_PB * D_;

    // stage slice kk into buffer buf: A = 320x32 f32 (XOR-swizzled 16B chunks:
    // LDS chunk pos (row,pc) holds global chunk pc ^ (row&7)); B = 10 x 1KB
    // fragments (slot f = plane*5+ct, staged by wave w=f). 5 loads/thread.
    auto stage = [&](int buf, int kk) {
        #pragma unroll
        for (int l = 0; l < 4; ++l) {
            int rb  = w * 4 + l;             // 0..39 (8-row groups)
            int row = rb * 8 + (lane >> 3);
            int pc  = lane & 7;
            int sc  = pc ^ (row & 7);
            const float* g = Abase + (size_t)row * D_ + kk * 32 + sc * 4;
            load_lds16(g, Sbuf[buf] + rb * 1024);   // dst wave-uniform
        }
        {
            int f     = w;                   // 0..9
            int plane = f / 5, ct = f % 5;
            const ushort* g = Wf + (size_t)plane * PLANE_STRIDE
                                 + (ct * NKK + kk) * FRAG + lane * 8;
            load_lds16(g, Sbuf[buf] + A_BYTES + f * 1024);
        }
    };

    f32x4 acc[2][5];
    #pragma unroll
    for (int t = 0; t < 2; ++t)
        #pragma unroll
        for (int ct = 0; ct < 5; ++ct)
            acc[t][ct] = (f32x4){0.f, 0.f, 0.f, 0.f};

    auto body = [&](int buf) {
        const float*  Ab = (const float*)(Sbuf[buf]);
        const ushort* Bb = (const ushort*)(Sbuf[buf] + A_BYTES);
        f16x8 a1f[2], a2f[2];
        #pragma unroll
        for (int t = 0; t < 2; ++t) {
            int rowl = w * 32 + t * 16 + n;
            int sw   = n & 7;                // rowl&7 == n&7 (base mult of 16)
            float4 f0 = *(const float4*)(Ab + rowl * 32 + (((2 * q)     ^ sw) * 4));
            float4 f1 = *(const float4*)(Ab + rowl * 32 + (((2 * q + 1) ^ sw) * 4));
            float v[8] = {f0.x, f0.y, f0.z, f0.w, f1.x, f1.y, f1.z, f1.w};
            #pragma unroll
            for (int j = 0; j < 8; ++j) {
                _Float16 h = (_Float16)v[j];
                a1f[t][j] = h;
                a2f[t][j] = (_Float16)(v[j] - (float)h);
            }
        }
        #pragma unroll
        for (int ct = 0; ct < 5; ++ct) {
            f16x8 b1 = *(const f16x8*)(Bb + ct * 512       + lane * 8);
            f16x8 b2 = *(const f16x8*)(Bb + (5 + ct) * 512 + lane * 8);
            acc[0][ct] = __builtin_amdgcn_mfma_f32_16x16x32_f16(a1f[0], b1, acc[0][ct], 0, 0, 0);
            acc[0][ct] = __builtin_amdgcn_mfma_f32_16x16x32_f16(a2f[0], b1, acc[0][ct], 0, 0, 0);
            acc[0][ct] = __builtin_amdgcn_mfma_f32_16x16x32_f16(a1f[0], b2, acc[0][ct], 0, 0, 0);
            acc[1][ct] = __builtin_amdgcn_mfma_f32_16x16x32_f16(a1f[1], b1, acc[1][ct], 0, 0, 0);
            acc[1][ct] = __builtin_amdgcn_mfma_f32_16x16x32_f16(a2f[1], b1, acc[1][ct], 0, 0, 0);
            acc[1][ct] = __builtin_amdgcn_mfma_f32_16x16x32_f16(a1f[1], b2, acc[1][ct], 0, 0, 0);
        }
    };

    // prologue: slices 0,1 in flight (10 loads/thread)
    stage(0, 0);
    stage(1, 1);

    for (int kk = 0; kk < 15; ++kk) {
        WAITVM(5);                           // own slice-k loads retired
        __builtin_amdgcn_s_barrier();        // everyone's slice k is in LDS
        if (kk <= 13) stage((kk + 2) % 3, kk + 2);  // overwrites buf read @ kk-1
        body(kk % 3);
    }
    WAITVM(0);                               // last slice (15)
    __builtin_amdgcn_s_barrier();
    body(0);                                 // 15 % 3 == 0

    // ---- epilogue: bias + argmax + softmax + nontemporal stores ----
    #pragma unroll
    for (int t = 0; t < 2; ++t) {
        float x[5][4];
        #pragma unroll
        for (int ct = 0; ct < 5; ++ct) {
            int c = ct * 16 + n;
            bool valid = (c < C_);
            float bv = valid ? bias[c] : 0.f;
            #pragma unroll
            for (int r = 0; r < 4; ++r)
                x[ct][r] = valid ? (acc[t][ct][r] + bv) : -INFINITY;
        }
        float av[4]; int ai[4];
        #pragma unroll
        for (int r = 0; r < 4; ++r) {
            av[r] = x[0][r]; ai[r] = n;
            #pragma unroll
            for (int ct = 1; ct < 5; ++ct) {
                int c = ct * 16 + n;
                if (x[ct][r] > av[r]) { av[r] = x[ct][r]; ai[r] = c; }
            }
        }
        #pragma unroll
        for (int off = 8; off >= 1; off >>= 1) {
            #pragma unroll
            for (int r = 0; r < 4; ++r) {
                float ov = __shfl_xor(av[r], off, 16);
                int   oi = __shfl_xor(ai[r], off, 16);
                if (ov > av[r] || (ov == av[r] && oi < ai[r])) { av[r] = ov; ai[r] = oi; }
            }
        }
        float s[4] = {0.f, 0.f, 0.f, 0.f};
        #pragma unroll
        for (int ct = 0; ct < 5; ++ct)
            #pragma unroll
            for (int r = 0; r < 4; ++r) {
                x[ct][r] = __expf(x[ct][r] - av[r]);   // -INF -> 0
                s[r] += x[ct][r];
            }
        #pragma unroll
        for (int off = 8; off >= 1; off >>= 1)
            #pragma unroll
            for (int r = 0; r < 4; ++r) s[r] += __shfl_xor(s[r], off, 16);

        const size_t growb = (size_t)blockIdx.x * ROWS_PB + w * 32 + t * 16 + q * 4;
        #pragma unroll
        for (int r = 0; r < 4; ++r) {
            float inv = 1.f / s[r];
            float* op = probs + (growb + r) * C_;
            #pragma unroll
            for (int ct = 0; ct < 5; ++ct) {
                int c = ct * 16 + n;
                if (c < C_) __builtin_nontemporal_store(x[ct][r] * inv, op + c);
            }
        }
        if (n == 0) {
            int rl = w * 32 + t * 16 + q * 4;   // 0..319
            #pragma unroll
            for (int r = 0; r < 4; ++r) {
                int rr = rl + r;
                best_s[rr / T_][rr % T_] = ai[r];
            }
        }
    }
    __syncthreads();

    // in-block CTC greedy decode (4 batch elements)
    if (tid < 4) {
        const int* bs = best_s[tid];
        float* op = lab + ((size_t)blockIdx.x * 4 + tid) * PRED_;
        int prev = -1, pos = 0;
        for (int t2 = 0; t2 < T_; ++t2) {
            int v = bs[t2];
            if (v != BLANK_ && v != prev) {
                if (pos < PRED_) op[pos] = (float)v;
                ++pos;
            }
            prev = v;
        }
        for (int i2 = (pos < PRED_ ? pos : PRED_); i2 < PRED_; ++i2) op[i2] = -1.f;
    }
}

extern "C" void kernel_launch(void* const* d_in, const int* in_sizes, int n_in,
                              void* d_out, int out_size, void* d_ws, size_t ws_size,
                              hipStream_t stream) {
    const float* feat = (const float*)d_in[0];   // fp32 [1024,80,512]
    const float* W    = (const float*)d_in[1];   // fp32 [512,78]
    const float* bias = (const float*)d_in[2];   // fp32 [78]
    // d_in[3]=y, d_in[4]=times : unused
    float*  probs = (float*)d_out;
    float*  lab   = probs + (size_t)B_ * T_ * C_;
    ushort* Wf    = (ushort*)d_ws;               // 163840 B scratch

    hipLaunchKernelGGL(prep_w, dim3(320), dim3(256), 0, stream, W, Wf);
    hipLaunchKernelGGL(gemm_ctc, dim3(B_ / 4), dim3(640), 0, stream,
                       feat, Wf, bias, probs, lab);
}